// Round 4
// baseline (435.882 us; speedup 1.0000x reference)
//
#include <hip/hip_runtime.h>
#include <cstdint>
#include <cstddef>

// IT_Fast_Attn: B=8, C=256, N=4096, 2 iterations. fp32 I/O, bf16 compute/storage.
// Round 4: ctx split-K 16 (occupancy), row-fastest grid for L2 A-reuse,
// fused LN256+transpose (writes Vb + VT / fp32 d_out in one pass).

using u16 = unsigned short;
using short8 = __attribute__((ext_vector_type(8))) short;
using bf16x8 = __attribute__((ext_vector_type(8))) __bf16;
using f32x4  = __attribute__((ext_vector_type(4))) float;
using i32x4  = __attribute__((ext_vector_type(4))) int;
using u16x4  = __attribute__((ext_vector_type(4))) u16;
using u16x8  = __attribute__((ext_vector_type(8))) u16;

__device__ __forceinline__ float b2f(u16 u) {
    union { unsigned u32; float f; } c; c.u32 = ((unsigned)u) << 16; return c.f;
}
__device__ __forceinline__ u16 f2b(float f) {
    union { float f; unsigned u; } c; c.f = f;
    unsigned r = c.u + 0x7FFFu + ((c.u >> 16) & 1u);
    return (u16)(r >> 16);
}
__device__ __forceinline__ void cvt(u16 a,  u16& o)   { o = a; }
__device__ __forceinline__ void cvt(float a, u16& o)  { o = f2b(a); }
__device__ __forceinline__ void cvt(float a, float& o){ o = a; }
__device__ __forceinline__ void cvt(u16 a,  float& o) { o = b2f(a); }

// ---------------------------------------------------------------------------
// BT GEMM: C[row,col] = sum_k A[row,k] * B[col,k].  BM=BN=128, BK=32.
// Row-fastest: rowBase = blockIdx.x (so col-tile siblings sharing A are 256
// dispatches apart -> same XCD -> L2 A-reuse). 4 waves 2x2, 4x4 MFMA/wave.
// SPLITA: A source switches to A2 at k==kSplit (MLP reads [OUT | V]).
// MODE: 0 = store bf16; 1 = atomicAdd fp32 (split-K);
//       3 = +bias(fp32), relu, store bf16; 4 = +2*Xres(bf16), store bf16.
// ---------------------------------------------------------------------------
template<int MODE, bool SPLITA>
__global__ __launch_bounds__(256)
void gemm_bt(const u16* __restrict__ A, const u16* __restrict__ A2,
             int kSplit, int lda, int lda2,
             const u16* __restrict__ B, int ldb, long strA, long strB,
             int kChunk, int nKsplit,
             float* __restrict__ outF, u16* __restrict__ outB,
             long sOF, long sOB, int ldo,
             const u16* __restrict__ Xres,   // MODE4: flat (rows,256) bf16
             const float* __restrict__ bias) // MODE3
{
    __shared__ short lsA[128 * 40];
    __shared__ short lsB[128 * 40];

    const int bz    = blockIdx.z;
    const int batch = bz / nKsplit;
    const int ks    = bz - batch * nKsplit;
    const u16* Ab = A + (size_t)batch * strA;
    const u16* Bb = B + (size_t)batch * strB;
    const int rowBase = blockIdx.x * 128;   // row-fastest
    const int colBase = blockIdx.y * 128;
    const int k0 = ks * kChunk;
    const int k1 = k0 + kChunk;

    const int t    = threadIdx.x;
    const int sRow = t >> 2;           // 0..63
    const int sKq  = (t & 3) << 3;     // 0,8,16,24

    const int lane = t & 63;
    const int wave = t >> 6;
    const int wr   = (wave >> 1) * 64;
    const int wc   = (wave & 1) * 64;
    const int mrow = lane & 15;
    const int q    = lane >> 4;

    const f32x4 fzero = {0.f, 0.f, 0.f, 0.f};
    f32x4 acc[4][4];
#pragma unroll
    for (int i = 0; i < 4; i++)
#pragma unroll
        for (int j = 0; j < 4; j++) acc[i][j] = fzero;

    const u16* qA0 = Ab + (size_t)(rowBase + sRow) * lda + sKq;
    const u16* qA1 = qA0 + (size_t)64 * lda;
    const u16* rA0 = nullptr; const u16* rA1 = nullptr;
    if (SPLITA) {
        rA0 = A2 + (size_t)(rowBase + sRow) * lda2 + sKq - kSplit;
        rA1 = rA0 + (size_t)64 * lda2;
    }
    const u16* pB0 = Bb + (size_t)(colBase + sRow) * ldb + sKq;
    const u16* pB1 = pB0 + (size_t)64 * ldb;

    i32x4 a0, a1, b0, b1;
    if (!SPLITA || k0 < kSplit) { a0 = *(const i32x4*)(qA0 + k0); a1 = *(const i32x4*)(qA1 + k0); }
    else                        { a0 = *(const i32x4*)(rA0 + k0); a1 = *(const i32x4*)(rA1 + k0); }
    b0 = *(const i32x4*)(pB0 + k0);
    b1 = *(const i32x4*)(pB1 + k0);

    for (int kk = k0; kk < k1; kk += 32) {
        __syncthreads();
        *(i32x4*)&lsA[sRow * 40 + sKq]        = a0;
        *(i32x4*)&lsA[(sRow + 64) * 40 + sKq] = a1;
        *(i32x4*)&lsB[sRow * 40 + sKq]        = b0;
        *(i32x4*)&lsB[(sRow + 64) * 40 + sKq] = b1;
        __syncthreads();
        const int kn = kk + 32;
        if (kn < k1) {
            if (!SPLITA || kn < kSplit) { a0 = *(const i32x4*)(qA0 + kn); a1 = *(const i32x4*)(qA1 + kn); }
            else                        { a0 = *(const i32x4*)(rA0 + kn); a1 = *(const i32x4*)(rA1 + kn); }
            b0 = *(const i32x4*)(pB0 + kn);
            b1 = *(const i32x4*)(pB1 + kn);
        }
        bf16x8 af[4], bfr[4];
#pragma unroll
        for (int mi = 0; mi < 4; mi++)
            af[mi] = __builtin_bit_cast(bf16x8,
                *(const short8*)&lsA[(wr + mi * 16 + mrow) * 40 + q * 8]);
#pragma unroll
        for (int ni = 0; ni < 4; ni++)
            bfr[ni] = __builtin_bit_cast(bf16x8,
                *(const short8*)&lsB[(wc + ni * 16 + mrow) * 40 + q * 8]);
#pragma unroll
        for (int mi = 0; mi < 4; mi++)
#pragma unroll
            for (int ni = 0; ni < 4; ni++)
                acc[mi][ni] = __builtin_amdgcn_mfma_f32_16x16x32_bf16(
                    af[mi], bfr[ni], acc[mi][ni], 0, 0, 0);
    }

    // epilogue: lane holds D[row = q*4+r][col = mrow] per 16x16 tile
#pragma unroll
    for (int mi = 0; mi < 4; mi++) {
#pragma unroll
        for (int ni = 0; ni < 4; ni++) {
            const int col = colBase + wc + ni * 16 + mrow;
#pragma unroll
            for (int r = 0; r < 4; r++) {
                const int row = rowBase + wr + mi * 16 + q * 4 + r;
                float v = acc[mi][ni][r];
                if (MODE == 0) {
                    outB[(size_t)batch * sOB + (size_t)row * ldo + col] = f2b(v);
                } else if (MODE == 1) {
                    atomicAdd(&outF[(size_t)batch * sOF + (size_t)row * ldo + col], v);
                } else if (MODE == 3) {
                    v += bias[col];
                    v = v > 0.f ? v : 0.f;
                    outB[(size_t)row * ldo + col] = f2b(v);
                } else if (MODE == 4) {
                    v += 2.f * b2f(Xres[(size_t)row * 256 + col]);
                    outB[(size_t)row * ldo + col] = f2b(v);
                }
            }
        }
    }
}

// ---------------------------------------------------------------------------
// Transpose (R x Cc) -> (Cc x R) per batch, with dtype conversion.
// ---------------------------------------------------------------------------
template<typename TIN, typename TOUT>
__global__ __launch_bounds__(256)
void transpose_k(const TIN* __restrict__ in, TOUT* __restrict__ out,
                 int R, int Cc, long sIn, long sOut)
{
    __shared__ TOUT tile[32][33];
    const int b = blockIdx.z;
    const TIN* ib = in + (size_t)b * sIn;
    TOUT* ob = out + (size_t)b * sOut;
    const int c0 = blockIdx.x * 32, r0 = blockIdx.y * 32;
    const int tx = threadIdx.x & 31, ty = threadIdx.x >> 5;
#pragma unroll
    for (int i = 0; i < 32; i += 8)
        cvt(ib[(size_t)(r0 + ty + i) * Cc + c0 + tx], tile[ty + i][tx]);
    __syncthreads();
#pragma unroll
    for (int i = 0; i < 32; i += 8)
        ob[(size_t)(c0 + ty + i) * R + r0 + tx] = tile[tx][ty + i];
}

// P = softmax(Xb rows of 256) bf16. One wave per row.
__global__ __launch_bounds__(256)
void softmax_k(const u16* __restrict__ Xb, u16* __restrict__ P)
{
    const int wave = threadIdx.x >> 6, lane = threadIdx.x & 63;
    const size_t row = (size_t)blockIdx.x * 4 + wave;
    const u16x4 xb = *(const u16x4*)(Xb + row * 256 + lane * 4);
    const float x0 = b2f(xb.x), x1 = b2f(xb.y), x2 = b2f(xb.z), x3 = b2f(xb.w);
    float m = fmaxf(fmaxf(x0, x1), fmaxf(x2, x3));
    for (int o = 32; o > 0; o >>= 1) m = fmaxf(m, __shfl_xor(m, o));
    const float e0 = __expf(x0 - m), e1 = __expf(x1 - m);
    const float e2 = __expf(x2 - m), e3 = __expf(x3 - m);
    float s = e0 + e1 + e2 + e3;
    for (int o = 32; o > 0; o >>= 1) s += __shfl_xor(s, o);
    const float inv = 1.f / s;
    u16x4 pv = { f2b(e0 * inv), f2b(e1 * inv), f2b(e2 * inv), f2b(e3 * inv) };
    *(u16x4*)(P + row * 256 + lane * 4) = pv;
}

// LN over virtual row [OUT(256) | V(256) | MLPo(512)] -> CAT row (1024) bf16.
__global__ __launch_bounds__(256)
void ln1024_k(const u16* __restrict__ OUT, const u16* __restrict__ V,
              const u16* __restrict__ MLPo, u16* __restrict__ CAT,
              const float* __restrict__ g, const float* __restrict__ be)
{
    const int wave = threadIdx.x >> 6, lane = threadIdx.x & 63;
    const size_t row = (size_t)blockIdx.x * 4 + wave;
    const int c = lane * 16;
    const u16* src;
    if (c < 256)       src = OUT  + row * 256 + c;
    else if (c < 512)  src = V    + row * 256 + (c - 256);
    else               src = MLPo + row * 512 + (c - 512);
    short8 r0 = *(const short8*)(src);
    short8 r1 = *(const short8*)(src + 8);
    float vals[16];
#pragma unroll
    for (int i = 0; i < 8; i++) {
        vals[i]     = b2f((u16)r0[i]);
        vals[8 + i] = b2f((u16)r1[i]);
    }
    float s = 0.f, s2 = 0.f;
#pragma unroll
    for (int i = 0; i < 16; i++) { s += vals[i]; s2 += vals[i] * vals[i]; }
    for (int o = 32; o > 0; o >>= 1) { s += __shfl_xor(s, o); s2 += __shfl_xor(s2, o); }
    const float mean = s * (1.f / 1024.f);
    const float var  = s2 * (1.f / 1024.f) - mean * mean;
    const float rstd = rsqrtf(var + 1e-5f);
    short8 o0, o1;
#pragma unroll
    for (int i = 0; i < 8; i++) {
        o0[i] = (short)f2b((vals[i]     - mean) * rstd * g[c + i]     + be[c + i]);
        o1[i] = (short)f2b((vals[8 + i] - mean) * rstd * g[c + 8 + i] + be[c + 8 + i]);
    }
    u16* dst = CAT + row * 1024 + c;
    *(short8*)(dst)     = o0;
    *(short8*)(dst + 8) = o1;
}

// ---------------------------------------------------------------------------
// Fused LN256 + transpose. Block = 32 rows (one batch stripe). 4 waves x 8
// sequential rows; LN per row via wave shuffle; normalized values staged in
// LDS (stride 266 u16 / 261 f32 -> column reads hit all 32 banks since
// 133,261 = 5 mod 32), then transposed 64B/128B-per-thread global writes.
// WRITE_VB: also store row-major bf16 Vb. OUTT: u16 (VT) or float (d_out).
// ---------------------------------------------------------------------------
template<typename OUTT, bool WRITE_VB>
__global__ __launch_bounds__(256)
void ln256t_k(const u16* __restrict__ Tb, const float* __restrict__ g,
              const float* __restrict__ be, u16* __restrict__ Vb,
              OUTT* __restrict__ outT)
{
    constexpr int STRIDE = (sizeof(OUTT) == 2) ? 266 : 261;
    __shared__ OUTT tile[32 * STRIDE];
    const int wid = threadIdx.x >> 6, lane = threadIdx.x & 63;
    const int bx = blockIdx.x;
    const size_t r0 = (size_t)bx * 32;
    const int b  = bx >> 7;            // 128 blocks per batch
    const int n0 = (bx & 127) * 32;

#pragma unroll
    for (int j = 0; j < 8; j++) {
        const int lr = wid * 8 + j;
        const size_t row = r0 + lr;
        const u16x4 tb = *(const u16x4*)(Tb + row * 256 + lane * 4);
        const float x0 = b2f(tb.x), x1 = b2f(tb.y), x2 = b2f(tb.z), x3 = b2f(tb.w);
        float s  = x0 + x1 + x2 + x3;
        float s2 = x0 * x0 + x1 * x1 + x2 * x2 + x3 * x3;
        for (int o = 32; o > 0; o >>= 1) { s += __shfl_xor(s, o); s2 += __shfl_xor(s2, o); }
        const float mean = s * (1.f / 256.f);
        const float var  = s2 * (1.f / 256.f) - mean * mean;
        const float rstd = rsqrtf(var + 1e-5f);
        const int c = lane * 4;
        float4 ov = { (x0 - mean) * rstd * g[c + 0] + be[c + 0],
                      (x1 - mean) * rstd * g[c + 1] + be[c + 1],
                      (x2 - mean) * rstd * g[c + 2] + be[c + 2],
                      (x3 - mean) * rstd * g[c + 3] + be[c + 3] };
        if (WRITE_VB) {
            u16x4 vb = { f2b(ov.x), f2b(ov.y), f2b(ov.z), f2b(ov.w) };
            *(u16x4*)(Vb + row * 256 + c) = vb;
        }
        OUTT* tl = &tile[lr * STRIDE + c];
        cvt(ov.x, tl[0]); cvt(ov.y, tl[1]); cvt(ov.z, tl[2]); cvt(ov.w, tl[3]);
    }
    __syncthreads();

    const int c = threadIdx.x;                      // output row (channel)
    OUTT* dst = outT + ((size_t)b * 256 + c) * 4096 + n0;
    if (sizeof(OUTT) == 2) {
#pragma unroll
        for (int k = 0; k < 4; k++) {
            u16x8 v;
#pragma unroll
            for (int i = 0; i < 8; i++) v[i] = *(const u16*)&tile[(k * 8 + i) * STRIDE + c];
            *(u16x8*)((u16*)dst + k * 8) = v;
        }
    } else {
#pragma unroll
        for (int k = 0; k < 8; k++) {
            float4 v;
            v.x = *(const float*)&tile[(k * 4 + 0) * STRIDE + c];
            v.y = *(const float*)&tile[(k * 4 + 1) * STRIDE + c];
            v.z = *(const float*)&tile[(k * 4 + 2) * STRIDE + c];
            v.w = *(const float*)&tile[(k * 4 + 3) * STRIDE + c];
            *(float4*)((float*)dst + k * 4) = v;
        }
    }
}

// Convert the three weight matrices fp32->bf16 in one launch (vec4 indices).
__global__ __launch_bounds__(256)
void wconv_k(const float* __restrict__ Wq, const float* __restrict__ Wm,
             const float* __restrict__ Wr, u16* __restrict__ oq,
             u16* __restrict__ om, u16* __restrict__ orr)
{
    const int i = blockIdx.x * 256 + threadIdx.x;   // 0..147455
    const float* src; u16* dst; int j;
    if (i < 16384)      { src = Wq; dst = oq;  j = i; }
    else if (i < 81920) { src = Wm; dst = om;  j = i - 16384; }
    else                { src = Wr; dst = orr; j = i - 81920; }
    const float4 v = ((const float4*)src)[j];
    u16x4 o = { f2b(v.x), f2b(v.y), f2b(v.z), f2b(v.w) };
    ((u16x4*)dst)[j] = o;
}

__global__ __launch_bounds__(256)
void f32_to_b16_k(const float* __restrict__ in, u16* __restrict__ out, int n4)
{
    const int i = blockIdx.x * 256 + threadIdx.x;
    if (i < n4) {
        const float4 v = ((const float4*)in)[i];
        u16x4 o = { f2b(v.x), f2b(v.y), f2b(v.z), f2b(v.w) };
        ((u16x4*)out)[i] = o;
    }
}

extern "C" void kernel_launch(void* const* d_in, const int* in_sizes, int n_in,
                              void* d_out, int out_size, void* d_ws, size_t ws_size,
                              hipStream_t stream)
{
    (void)in_sizes; (void)n_in; (void)out_size; (void)ws_size;
    const float* x    = (const float*)d_in[0];
    const float* Wqkv = (const float*)d_in[1];
    const float* Wmlp = (const float*)d_in[2];
    const float* bmlp = (const float*)d_in[3];
    const float* g1   = (const float*)d_in[4];
    const float* be1  = (const float*)d_in[5];
    const float* Wres = (const float*)d_in[6];
    const float* g2   = (const float*)d_in[7];
    const float* be2  = (const float*)d_in[8];

    // workspace layout (all bf16 unless noted); ws_size = 256 MiB
    char* ws = (char*)d_ws;
    u16*   Xb   = (u16*)ws;   ws += (size_t)16777216;   // (32768,256)
    u16*   XT   = (u16*)ws;   ws += (size_t)16777216;   // (B,256,4096)
    u16*   Vb   = (u16*)ws;   ws += (size_t)16777216;   // (32768,256)
    u16*   VT2  = (u16*)ws;   ws += (size_t)16777216;   // (B,256,4096)
    u16*   OUT  = (u16*)ws;   ws += (size_t)16777216;   // (32768,256)
    u16*   MLPo = (u16*)ws;   ws += (size_t)33554432;   // (32768,512)
    u16*   CAT  = (u16*)ws;   ws += (size_t)67108864;   // (32768,1024)
    u16*   P    = (u16*)ws;   ws += (size_t)16777216;   // (32768,256)
    u16*   Tb   = (u16*)ws;   ws += (size_t)16777216;   // (32768,256)
    float* ctxf = (float*)ws; ws += (size_t)2097152;    // (B,256,256) fp32
    u16*   ctxb = (u16*)ws;   ws += (size_t)1048576;    // (B,256,256)
    u16*   Wq_b = (u16*)ws;   ws += (size_t)131072;     // (256,256)
    u16*   Wm_b = (u16*)ws;   ws += (size_t)524288;     // (512,512)
    u16*   Wr_b = (u16*)ws;   ws += (size_t)524288;     // (256,1024)
    u16*   xt   = CAT;  // alias: xt dead after gemm1; CAT first written in-iter

    const int BIG = 1 << 30;

    // 0. weights fp32 -> bf16 (one launch)
    wconv_k<<<dim3(576), 256, 0, stream>>>(Wqkv, Wmlp, Wres, Wq_b, Wm_b, Wr_b);

    // 1. xt = transpose(x): per batch (256,4096) fp32 -> (4096,256) bf16
    transpose_k<float, u16><<<dim3(128, 8, 8), 256, 0, stream>>>(
        x, xt, 256, 4096, 256L * 4096, 4096L * 256);

    // 2. Xb = xt @ Wqkv^T bf16   [M=32768,N=256,K=256]  grid (rows, cols)
    gemm_bt<0, false><<<dim3(256, 2, 1), 256, 0, stream>>>(
        xt, nullptr, BIG, 256, 0, Wq_b, 256, 0, 0, 256, 1,
        nullptr, Xb, 0, 0, 256, nullptr, nullptr);

    // 3. XT = transpose(Xb): per batch (4096,256) -> (256,4096)
    transpose_k<u16, u16><<<dim3(8, 128, 8), 256, 0, stream>>>(
        Xb, XT, 4096, 256, 4096L * 256, 256L * 4096);

    const u16* VTcur = XT;   // v = x initially
    const u16* Vcur  = Xb;

    for (int it = 0; it < 2; ++it) {
        // P = softmax(Xb rows)
        softmax_k<<<dim3(8192), 256, 0, stream>>>(Xb, P);

        // ctxT[d,c] = sum_n VT[d,n] * XT[c,n]  (split-K=16, fp32 atomics)
        hipMemsetAsync(ctxf, 0, (size_t)8 * 256 * 256 * sizeof(float), stream);
        gemm_bt<1, false><<<dim3(2, 2, 128), 256, 0, stream>>>(
            VTcur, nullptr, BIG, 4096, 0, XT, 4096, 1048576, 1048576, 256, 16,
            ctxf, nullptr, 65536, 0, 256, nullptr, nullptr);
        f32_to_b16_k<<<dim3(512), 256, 0, stream>>>(ctxf, ctxb, 131072);

        // OUT = P @ ctxT^T   [per batch M=4096,N=256,K=256]
        gemm_bt<0, false><<<dim3(32, 2, 8), 256, 0, stream>>>(
            P, nullptr, BIG, 256, 0, ctxb, 256, 1048576, 65536, 256, 1,
            nullptr, OUT, 0, 1048576, 256, nullptr, nullptr);

        // MLPo = relu([OUT | Vcur] @ Wmlp^T + b)  [M=32768,N=512,K=512 split@256]
        gemm_bt<3, true><<<dim3(256, 4, 1), 256, 0, stream>>>(
            OUT, Vcur, 256, 256, 256, Wm_b, 512, 0, 0, 512, 1,
            nullptr, MLPo, 0, 0, 512, nullptr, bmlp);

        // CAT = LN1024([OUT | Vcur | MLPo])
        ln1024_k<<<dim3(8192), 256, 0, stream>>>(OUT, Vcur, MLPo, CAT, g1, be1);

        // Tb = CAT @ Wres^T + 2*Xb  bf16  [M=32768,N=256,K=1024]
        gemm_bt<4, false><<<dim3(256, 2, 1), 256, 0, stream>>>(
            CAT, nullptr, BIG, 1024, 0, Wr_b, 1024, 0, 0, 1024, 1,
            nullptr, Tb, 0, 0, 256, Xb, nullptr);

        // LN256 + transpose fused
        if (it == 0) {
            ln256t_k<u16, true><<<dim3(1024), 256, 0, stream>>>(
                Tb, g2, be2, Vb, VT2);
            VTcur = VT2;
            Vcur  = Vb;
        } else {
            ln256t_k<float, false><<<dim3(1024), 256, 0, stream>>>(
                Tb, g2, be2, nullptr, (float*)d_out);
        }
    }
}

// Round 5
// 412.558 us; speedup vs baseline: 1.0565x; 1.0565x over previous
//
#include <hip/hip_runtime.h>
#include <cstdint>
#include <cstddef>

// IT_Fast_Attn: B=8, C=256, N=4096, 2 iterations. fp32 I/O, bf16 compute/storage.
// Round 5: col-fastest grid restored (r4 row-fastest regressed L2 A-reuse);
// ctx split-K via private partial buffers + reduce (no atomics, no memset).

using u16 = unsigned short;
using short8 = __attribute__((ext_vector_type(8))) short;
using bf16x8 = __attribute__((ext_vector_type(8))) __bf16;
using f32x4  = __attribute__((ext_vector_type(4))) float;
using i32x4  = __attribute__((ext_vector_type(4))) int;
using u16x4  = __attribute__((ext_vector_type(4))) u16;
using u16x8  = __attribute__((ext_vector_type(8))) u16;

__device__ __forceinline__ float b2f(u16 u) {
    union { unsigned u32; float f; } c; c.u32 = ((unsigned)u) << 16; return c.f;
}
__device__ __forceinline__ u16 f2b(float f) {
    union { float f; unsigned u; } c; c.f = f;
    unsigned r = c.u + 0x7FFFu + ((c.u >> 16) & 1u);
    return (u16)(r >> 16);
}
__device__ __forceinline__ void cvt(u16 a,  u16& o)   { o = a; }
__device__ __forceinline__ void cvt(float a, u16& o)  { o = f2b(a); }
__device__ __forceinline__ void cvt(float a, float& o){ o = a; }
__device__ __forceinline__ void cvt(u16 a,  float& o) { o = b2f(a); }

// ---------------------------------------------------------------------------
// BT GEMM: C[row,col] = sum_k A[row,k] * B[col,k].  BM=BN=128, BK=32.
// COL-fastest grid (colBase = blockIdx.x): consecutive blocks share the same
// A row-stripe -> immediate L2 reuse (r3-measured; r4 row-fastest regressed).
// 4 waves 2x2, each 4x4 grid of 16x16x32 bf16 MFMAs. LDS stride 40 (2-way, free).
// SPLITA: A source switches to A2 at k==kSplit (MLP reads [OUT | V]).
// MODE: 0 = store bf16; 1 = store fp32 partial per ks-slice (split-K, no atomics);
//       3 = +bias(fp32), relu, store bf16; 4 = +2*Xres(bf16), store bf16.
// ---------------------------------------------------------------------------
template<int MODE, bool SPLITA>
__global__ __launch_bounds__(256)
void gemm_bt(const u16* __restrict__ A, const u16* __restrict__ A2,
             int kSplit, int lda, int lda2,
             const u16* __restrict__ B, int ldb, long strA, long strB,
             int kChunk, int nKsplit,
             float* __restrict__ outF, u16* __restrict__ outB,
             long sOF, long sOB, int ldo,
             const u16* __restrict__ Xres,   // MODE4: flat (rows,256) bf16
             const float* __restrict__ bias) // MODE3
{
    __shared__ short lsA[128 * 40];
    __shared__ short lsB[128 * 40];

    const int bz    = blockIdx.z;
    const int batch = bz / nKsplit;
    const int ks    = bz - batch * nKsplit;
    const u16* Ab = A + (size_t)batch * strA;
    const u16* Bb = B + (size_t)batch * strB;
    const int colBase = blockIdx.x * 128;   // col-fastest
    const int rowBase = blockIdx.y * 128;
    const int k0 = ks * kChunk;
    const int k1 = k0 + kChunk;

    const int t    = threadIdx.x;
    const int sRow = t >> 2;           // 0..63
    const int sKq  = (t & 3) << 3;     // 0,8,16,24

    const int lane = t & 63;
    const int wave = t >> 6;
    const int wr   = (wave >> 1) * 64;
    const int wc   = (wave & 1) * 64;
    const int mrow = lane & 15;
    const int q    = lane >> 4;

    const f32x4 fzero = {0.f, 0.f, 0.f, 0.f};
    f32x4 acc[4][4];
#pragma unroll
    for (int i = 0; i < 4; i++)
#pragma unroll
        for (int j = 0; j < 4; j++) acc[i][j] = fzero;

    const u16* qA0 = Ab + (size_t)(rowBase + sRow) * lda + sKq;
    const u16* qA1 = qA0 + (size_t)64 * lda;
    const u16* rA0 = nullptr; const u16* rA1 = nullptr;
    if (SPLITA) {
        rA0 = A2 + (size_t)(rowBase + sRow) * lda2 + sKq - kSplit;
        rA1 = rA0 + (size_t)64 * lda2;
    }
    const u16* pB0 = Bb + (size_t)(colBase + sRow) * ldb + sKq;
    const u16* pB1 = pB0 + (size_t)64 * ldb;

    i32x4 a0, a1, b0, b1;
    if (!SPLITA || k0 < kSplit) { a0 = *(const i32x4*)(qA0 + k0); a1 = *(const i32x4*)(qA1 + k0); }
    else                        { a0 = *(const i32x4*)(rA0 + k0); a1 = *(const i32x4*)(rA1 + k0); }
    b0 = *(const i32x4*)(pB0 + k0);
    b1 = *(const i32x4*)(pB1 + k0);

    for (int kk = k0; kk < k1; kk += 32) {
        __syncthreads();
        *(i32x4*)&lsA[sRow * 40 + sKq]        = a0;
        *(i32x4*)&lsA[(sRow + 64) * 40 + sKq] = a1;
        *(i32x4*)&lsB[sRow * 40 + sKq]        = b0;
        *(i32x4*)&lsB[(sRow + 64) * 40 + sKq] = b1;
        __syncthreads();
        const int kn = kk + 32;
        if (kn < k1) {
            if (!SPLITA || kn < kSplit) { a0 = *(const i32x4*)(qA0 + kn); a1 = *(const i32x4*)(qA1 + kn); }
            else                        { a0 = *(const i32x4*)(rA0 + kn); a1 = *(const i32x4*)(rA1 + kn); }
            b0 = *(const i32x4*)(pB0 + kn);
            b1 = *(const i32x4*)(pB1 + kn);
        }
        bf16x8 af[4], bfr[4];
#pragma unroll
        for (int mi = 0; mi < 4; mi++)
            af[mi] = __builtin_bit_cast(bf16x8,
                *(const short8*)&lsA[(wr + mi * 16 + mrow) * 40 + q * 8]);
#pragma unroll
        for (int ni = 0; ni < 4; ni++)
            bfr[ni] = __builtin_bit_cast(bf16x8,
                *(const short8*)&lsB[(wc + ni * 16 + mrow) * 40 + q * 8]);
#pragma unroll
        for (int mi = 0; mi < 4; mi++)
#pragma unroll
            for (int ni = 0; ni < 4; ni++)
                acc[mi][ni] = __builtin_amdgcn_mfma_f32_16x16x32_bf16(
                    af[mi], bfr[ni], acc[mi][ni], 0, 0, 0);
    }

    // epilogue: lane holds D[row = q*4+r][col = mrow] per 16x16 tile
#pragma unroll
    for (int mi = 0; mi < 4; mi++) {
#pragma unroll
        for (int ni = 0; ni < 4; ni++) {
            const int col = colBase + wc + ni * 16 + mrow;
#pragma unroll
            for (int r = 0; r < 4; r++) {
                const int row = rowBase + wr + mi * 16 + q * 4 + r;
                float v = acc[mi][ni][r];
                if (MODE == 0) {
                    outB[(size_t)batch * sOB + (size_t)row * ldo + col] = f2b(v);
                } else if (MODE == 1) {
                    outF[((size_t)batch * nKsplit + ks) * sOF
                         + (size_t)row * ldo + col] = v;
                } else if (MODE == 3) {
                    v += bias[col];
                    v = v > 0.f ? v : 0.f;
                    outB[(size_t)row * ldo + col] = f2b(v);
                } else if (MODE == 4) {
                    v += 2.f * b2f(Xres[(size_t)row * 256 + col]);
                    outB[(size_t)row * ldo + col] = f2b(v);
                }
            }
        }
    }
}

// ---------------------------------------------------------------------------
// Transpose (R x Cc) -> (Cc x R) per batch, with dtype conversion.
// ---------------------------------------------------------------------------
template<typename TIN, typename TOUT>
__global__ __launch_bounds__(256)
void transpose_k(const TIN* __restrict__ in, TOUT* __restrict__ out,
                 int R, int Cc, long sIn, long sOut)
{
    __shared__ TOUT tile[32][33];
    const int b = blockIdx.z;
    const TIN* ib = in + (size_t)b * sIn;
    TOUT* ob = out + (size_t)b * sOut;
    const int c0 = blockIdx.x * 32, r0 = blockIdx.y * 32;
    const int tx = threadIdx.x & 31, ty = threadIdx.x >> 5;
#pragma unroll
    for (int i = 0; i < 32; i += 8)
        cvt(ib[(size_t)(r0 + ty + i) * Cc + c0 + tx], tile[ty + i][tx]);
    __syncthreads();
#pragma unroll
    for (int i = 0; i < 32; i += 8)
        ob[(size_t)(c0 + ty + i) * R + r0 + tx] = tile[tx][ty + i];
}

// P = softmax(Xb rows of 256) bf16. One wave per row.
__global__ __launch_bounds__(256)
void softmax_k(const u16* __restrict__ Xb, u16* __restrict__ P)
{
    const int wave = threadIdx.x >> 6, lane = threadIdx.x & 63;
    const size_t row = (size_t)blockIdx.x * 4 + wave;
    const u16x4 xb = *(const u16x4*)(Xb + row * 256 + lane * 4);
    const float x0 = b2f(xb.x), x1 = b2f(xb.y), x2 = b2f(xb.z), x3 = b2f(xb.w);
    float m = fmaxf(fmaxf(x0, x1), fmaxf(x2, x3));
    for (int o = 32; o > 0; o >>= 1) m = fmaxf(m, __shfl_xor(m, o));
    const float e0 = __expf(x0 - m), e1 = __expf(x1 - m);
    const float e2 = __expf(x2 - m), e3 = __expf(x3 - m);
    float s = e0 + e1 + e2 + e3;
    for (int o = 32; o > 0; o >>= 1) s += __shfl_xor(s, o);
    const float inv = 1.f / s;
    u16x4 pv = { f2b(e0 * inv), f2b(e1 * inv), f2b(e2 * inv), f2b(e3 * inv) };
    *(u16x4*)(P + row * 256 + lane * 4) = pv;
}

// LN over virtual row [OUT(256) | V(256) | MLPo(512)] -> CAT row (1024) bf16.
__global__ __launch_bounds__(256)
void ln1024_k(const u16* __restrict__ OUT, const u16* __restrict__ V,
              const u16* __restrict__ MLPo, u16* __restrict__ CAT,
              const float* __restrict__ g, const float* __restrict__ be)
{
    const int wave = threadIdx.x >> 6, lane = threadIdx.x & 63;
    const size_t row = (size_t)blockIdx.x * 4 + wave;
    const int c = lane * 16;
    const u16* src;
    if (c < 256)       src = OUT  + row * 256 + c;
    else if (c < 512)  src = V    + row * 256 + (c - 256);
    else               src = MLPo + row * 512 + (c - 512);
    short8 r0 = *(const short8*)(src);
    short8 r1 = *(const short8*)(src + 8);
    float vals[16];
#pragma unroll
    for (int i = 0; i < 8; i++) {
        vals[i]     = b2f((u16)r0[i]);
        vals[8 + i] = b2f((u16)r1[i]);
    }
    float s = 0.f, s2 = 0.f;
#pragma unroll
    for (int i = 0; i < 16; i++) { s += vals[i]; s2 += vals[i] * vals[i]; }
    for (int o = 32; o > 0; o >>= 1) { s += __shfl_xor(s, o); s2 += __shfl_xor(s2, o); }
    const float mean = s * (1.f / 1024.f);
    const float var  = s2 * (1.f / 1024.f) - mean * mean;
    const float rstd = rsqrtf(var + 1e-5f);
    short8 o0, o1;
#pragma unroll
    for (int i = 0; i < 8; i++) {
        o0[i] = (short)f2b((vals[i]     - mean) * rstd * g[c + i]     + be[c + i]);
        o1[i] = (short)f2b((vals[8 + i] - mean) * rstd * g[c + 8 + i] + be[c + 8 + i]);
    }
    u16* dst = CAT + row * 1024 + c;
    *(short8*)(dst)     = o0;
    *(short8*)(dst + 8) = o1;
}

// ---------------------------------------------------------------------------
// Fused LN256 + transpose. Block = 32 rows; LN via wave shuffle; normalized
// values staged in LDS (stride 266 u16 / 261 f32 -> conflict-free column
// reads), then transposed coalesced global writes.
// ---------------------------------------------------------------------------
template<typename OUTT, bool WRITE_VB>
__global__ __launch_bounds__(256)
void ln256t_k(const u16* __restrict__ Tb, const float* __restrict__ g,
              const float* __restrict__ be, u16* __restrict__ Vb,
              OUTT* __restrict__ outT)
{
    constexpr int STRIDE = (sizeof(OUTT) == 2) ? 266 : 261;
    __shared__ OUTT tile[32 * STRIDE];
    const int wid = threadIdx.x >> 6, lane = threadIdx.x & 63;
    const int bx = blockIdx.x;
    const size_t r0 = (size_t)bx * 32;
    const int b  = bx >> 7;            // 128 blocks per batch
    const int n0 = (bx & 127) * 32;

#pragma unroll
    for (int j = 0; j < 8; j++) {
        const int lr = wid * 8 + j;
        const size_t row = r0 + lr;
        const u16x4 tb = *(const u16x4*)(Tb + row * 256 + lane * 4);
        const float x0 = b2f(tb.x), x1 = b2f(tb.y), x2 = b2f(tb.z), x3 = b2f(tb.w);
        float s  = x0 + x1 + x2 + x3;
        float s2 = x0 * x0 + x1 * x1 + x2 * x2 + x3 * x3;
        for (int o = 32; o > 0; o >>= 1) { s += __shfl_xor(s, o); s2 += __shfl_xor(s2, o); }
        const float mean = s * (1.f / 256.f);
        const float var  = s2 * (1.f / 256.f) - mean * mean;
        const float rstd = rsqrtf(var + 1e-5f);
        const int c = lane * 4;
        float4 ov = { (x0 - mean) * rstd * g[c + 0] + be[c + 0],
                      (x1 - mean) * rstd * g[c + 1] + be[c + 1],
                      (x2 - mean) * rstd * g[c + 2] + be[c + 2],
                      (x3 - mean) * rstd * g[c + 3] + be[c + 3] };
        if (WRITE_VB) {
            u16x4 vb = { f2b(ov.x), f2b(ov.y), f2b(ov.z), f2b(ov.w) };
            *(u16x4*)(Vb + row * 256 + c) = vb;
        }
        OUTT* tl = &tile[lr * STRIDE + c];
        cvt(ov.x, tl[0]); cvt(ov.y, tl[1]); cvt(ov.z, tl[2]); cvt(ov.w, tl[3]);
    }
    __syncthreads();

    const int c = threadIdx.x;                      // output row (channel)
    OUTT* dst = outT + ((size_t)b * 256 + c) * 4096 + n0;
    if (sizeof(OUTT) == 2) {
#pragma unroll
        for (int k = 0; k < 4; k++) {
            u16x8 v;
#pragma unroll
            for (int i = 0; i < 8; i++) v[i] = *(const u16*)&tile[(k * 8 + i) * STRIDE + c];
            *(u16x8*)((u16*)dst + k * 8) = v;
        }
    } else {
#pragma unroll
        for (int k = 0; k < 8; k++) {
            float4 v;
            v.x = *(const float*)&tile[(k * 4 + 0) * STRIDE + c];
            v.y = *(const float*)&tile[(k * 4 + 1) * STRIDE + c];
            v.z = *(const float*)&tile[(k * 4 + 2) * STRIDE + c];
            v.w = *(const float*)&tile[(k * 4 + 3) * STRIDE + c];
            *(float4*)((float*)dst + k * 4) = v;
        }
    }
}

// Reduce 16 split-K partial fp32 ctx buffers -> bf16. One float4 per thread.
__global__ __launch_bounds__(256)
void ctxreduce_k(const float* __restrict__ ctxp, u16* __restrict__ ctxb)
{
    const int i = blockIdx.x * 256 + threadIdx.x;   // float4 id, 0..131071
    const int batch  = i >> 14;                     // 16384 float4 per batch
    const int within = i & 16383;
    const float4* src = (const float4*)ctxp + (size_t)batch * 16 * 16384 + within;
    float4 s = {0.f, 0.f, 0.f, 0.f};
#pragma unroll
    for (int ks = 0; ks < 16; ks++) {
        const float4 v = src[(size_t)ks * 16384];
        s.x += v.x; s.y += v.y; s.z += v.z; s.w += v.w;
    }
    u16x4 o = { f2b(s.x), f2b(s.y), f2b(s.z), f2b(s.w) };
    ((u16x4*)ctxb)[i] = o;
}

// Convert the three weight matrices fp32->bf16 in one launch (vec4 indices).
__global__ __launch_bounds__(256)
void wconv_k(const float* __restrict__ Wq, const float* __restrict__ Wm,
             const float* __restrict__ Wr, u16* __restrict__ oq,
             u16* __restrict__ om, u16* __restrict__ orr)
{
    const int i = blockIdx.x * 256 + threadIdx.x;   // 0..147455
    const float* src; u16* dst; int j;
    if (i < 16384)      { src = Wq; dst = oq;  j = i; }
    else if (i < 81920) { src = Wm; dst = om;  j = i - 16384; }
    else                { src = Wr; dst = orr; j = i - 81920; }
    const float4 v = ((const float4*)src)[j];
    u16x4 o = { f2b(v.x), f2b(v.y), f2b(v.z), f2b(v.w) };
    ((u16x4*)dst)[j] = o;
}

extern "C" void kernel_launch(void* const* d_in, const int* in_sizes, int n_in,
                              void* d_out, int out_size, void* d_ws, size_t ws_size,
                              hipStream_t stream)
{
    (void)in_sizes; (void)n_in; (void)out_size; (void)ws_size;
    const float* x    = (const float*)d_in[0];
    const float* Wqkv = (const float*)d_in[1];
    const float* Wmlp = (const float*)d_in[2];
    const float* bmlp = (const float*)d_in[3];
    const float* g1   = (const float*)d_in[4];
    const float* be1  = (const float*)d_in[5];
    const float* Wres = (const float*)d_in[6];
    const float* g2   = (const float*)d_in[7];
    const float* be2  = (const float*)d_in[8];

    // workspace layout (bf16 unless noted); total ~242 MiB of 256
    char* ws = (char*)d_ws;
    u16*   Xb   = (u16*)ws;   ws += (size_t)16777216;   // (32768,256)
    u16*   XT   = (u16*)ws;   ws += (size_t)16777216;   // (B,256,4096)
    u16*   Vb   = (u16*)ws;   ws += (size_t)16777216;   // (32768,256)
    u16*   VT2  = (u16*)ws;   ws += (size_t)16777216;   // (B,256,4096)
    u16*   OUT  = (u16*)ws;   ws += (size_t)16777216;   // (32768,256)
    u16*   MLPo = (u16*)ws;   ws += (size_t)33554432;   // (32768,512)
    u16*   CAT  = (u16*)ws;   ws += (size_t)67108864;   // (32768,1024)
    u16*   P    = (u16*)ws;   ws += (size_t)16777216;   // (32768,256)
    u16*   Tb   = (u16*)ws;   ws += (size_t)16777216;   // (32768,256)
    float* ctxp = (float*)ws; ws += (size_t)33554432;   // (B*16,256,256) fp32 partials
    u16*   ctxb = (u16*)ws;   ws += (size_t)1048576;    // (B,256,256)
    u16*   Wq_b = (u16*)ws;   ws += (size_t)131072;     // (256,256)
    u16*   Wm_b = (u16*)ws;   ws += (size_t)524288;     // (512,512)
    u16*   Wr_b = (u16*)ws;   ws += (size_t)524288;     // (256,1024)
    u16*   xt   = CAT;  // alias: xt dead after gemm1; CAT first written in-iter

    const int BIG = 1 << 30;

    // 0. weights fp32 -> bf16 (one launch)
    wconv_k<<<dim3(576), 256, 0, stream>>>(Wqkv, Wmlp, Wres, Wq_b, Wm_b, Wr_b);

    // 1. xt = transpose(x): per batch (256,4096) fp32 -> (4096,256) bf16
    transpose_k<float, u16><<<dim3(128, 8, 8), 256, 0, stream>>>(
        x, xt, 256, 4096, 256L * 4096, 4096L * 256);

    // 2. Xb = xt @ Wqkv^T bf16   [M=32768,N=256,K=256]  grid (cols, rows)
    gemm_bt<0, false><<<dim3(2, 256, 1), 256, 0, stream>>>(
        xt, nullptr, BIG, 256, 0, Wq_b, 256, 0, 0, 256, 1,
        nullptr, Xb, 0, 0, 256, nullptr, nullptr);

    // 3. XT = transpose(Xb): per batch (4096,256) -> (256,4096)
    transpose_k<u16, u16><<<dim3(8, 128, 8), 256, 0, stream>>>(
        Xb, XT, 4096, 256, 4096L * 256, 256L * 4096);

    const u16* VTcur = XT;   // v = x initially
    const u16* Vcur  = Xb;

    for (int it = 0; it < 2; ++it) {
        // P = softmax(Xb rows)
        softmax_k<<<dim3(8192), 256, 0, stream>>>(Xb, P);

        // ctxT[d,c] = sum_n VT[d,n] * XT[c,n]  (split-K=16, private partials)
        gemm_bt<1, false><<<dim3(2, 2, 128), 256, 0, stream>>>(
            VTcur, nullptr, BIG, 4096, 0, XT, 4096, 1048576, 1048576, 256, 16,
            ctxp, nullptr, 65536, 0, 256, nullptr, nullptr);
        ctxreduce_k<<<dim3(512), 256, 0, stream>>>(ctxp, ctxb);

        // OUT = P @ ctxT^T   [per batch M=4096,N=256,K=256]
        gemm_bt<0, false><<<dim3(2, 32, 8), 256, 0, stream>>>(
            P, nullptr, BIG, 256, 0, ctxb, 256, 1048576, 65536, 256, 1,
            nullptr, OUT, 0, 1048576, 256, nullptr, nullptr);

        // MLPo = relu([OUT | Vcur] @ Wmlp^T + b)  [M=32768,N=512,K=512 split@256]
        gemm_bt<3, true><<<dim3(4, 256, 1), 256, 0, stream>>>(
            OUT, Vcur, 256, 256, 256, Wm_b, 512, 0, 0, 512, 1,
            nullptr, MLPo, 0, 0, 512, nullptr, bmlp);

        // CAT = LN1024([OUT | Vcur | MLPo])
        ln1024_k<<<dim3(8192), 256, 0, stream>>>(OUT, Vcur, MLPo, CAT, g1, be1);

        // Tb = CAT @ Wres^T + 2*Xb  bf16  [M=32768,N=256,K=1024]
        gemm_bt<4, false><<<dim3(2, 256, 1), 256, 0, stream>>>(
            CAT, nullptr, BIG, 1024, 0, Wr_b, 1024, 0, 0, 1024, 1,
            nullptr, Tb, 0, 0, 256, Xb, nullptr);

        // LN256 + transpose fused
        if (it == 0) {
            ln256t_k<u16, true><<<dim3(1024), 256, 0, stream>>>(
                Tb, g2, be2, Vb, VT2);
            VTcur = VT2;
            Vcur  = Vb;
        } else {
            ln256t_k<float, false><<<dim3(1024), 256, 0, stream>>>(
                Tb, g2, be2, nullptr, (float*)d_out);
        }
    }
}